// Round 1
// 419.073 us; speedup vs baseline: 1.0218x; 1.0218x over previous
//
#include <hip/hip_runtime.h>

// x: (4, 4096, 4096) fp32. Row = 4096 = 32 heads x 128 dims.
// out[b,s,h*128+d] = (1/sqrt(32)) * sum_{h'} (-1)^popcount(h&h') x[b,s,h'*128+d]
// 32-pt FWHT across heads for each dim d, per row.
//
// Thread layout: 128 threads per row. r = t & 127; j = r & 3 (head mod 4),
// d4 = r >> 2 (dim-group of 4 floats, 0..31). Each thread holds the 8 heads
// {j, j+4, ..., j+28} for its dim-group: 8 float4 = 32 data VGPRs.
// FWHT stages 4/8/16 are in-register (partner head in same thread);
// stages 1/2 are __shfl_xor lane^1 / lane^2 (j = lane&3 -> quad_perm DPP, VALU-cheap).
//
// This round: global traffic is pure streaming (each line touched once, no
// cross-iteration reuse -- harness poison fills flush L2/L3 every iter), so
// mark all loads/stores non-temporal (nt flag on global_load/store_dwordx4)
// to avoid cache-allocate/evict overhead in TCC.

typedef float f32x4 __attribute__((ext_vector_type(4)));

__global__ __launch_bounds__(256) void fwht_heads_shfl_nt(
    const f32x4* __restrict__ x, f32x4* __restrict__ out, int total_threads) {
    int t = blockIdx.x * blockDim.x + threadIdx.x;
    if (t >= total_threads) return;
    int row = t >> 7;          // 128 threads per row
    int r = t & 127;
    int j = r & 3;             // head mod 4 -> shuffle partner = lane^1, lane^2
    int d4 = r >> 2;           // dim-group 0..31

    int base = row * 1024 + j * 32 + d4;   // float4 index
    const f32x4* __restrict__ xp = x + base;

    f32x4 v[8];                // v[k] = head j + 4k
#pragma unroll
    for (int k = 0; k < 8; ++k) v[k] = __builtin_nontemporal_load(xp + k * 128);

    // stages s=4,8,16 over head -> stride 1,2,4 over k (in-register)
#pragma unroll
    for (int s = 1; s < 8; s <<= 1) {
#pragma unroll
        for (int k = 0; k < 8; ++k) {
            if ((k & s) == 0) {
                int m = k | s;
                f32x4 a = v[k], b = v[m];
                v[k] = a + b;
                v[m] = a - b;
            }
        }
    }

    // stages s=1 (lane^1, sign from j&1) and s=2 (lane^2, sign from j&2)
    f32x4 sg1 = (j & 1) ? -1.0f : 1.0f;   // splat
    f32x4 sg2 = (j & 2) ? -1.0f : 1.0f;   // splat
#pragma unroll
    for (int k = 0; k < 8; ++k) {
        f32x4 o = v[k];
        f32x4 p;
#pragma unroll
        for (int c = 0; c < 4; ++c) p[c] = __shfl_xor(o[c], 1);
        o = sg1 * o + p;
#pragma unroll
        for (int c = 0; c < 4; ++c) p[c] = __shfl_xor(o[c], 2);
        v[k] = sg2 * o + p;
    }

    const float scale = 0.17677669529663687f;  // 1/sqrt(32)
    f32x4* __restrict__ op = out + base;
#pragma unroll
    for (int k = 0; k < 8; ++k) {
        __builtin_nontemporal_store(v[k] * scale, op + k * 128);
    }
}

extern "C" void kernel_launch(void* const* d_in, const int* in_sizes, int n_in,
                              void* d_out, int out_size, void* d_ws, size_t ws_size,
                              hipStream_t stream) {
    const f32x4* x = (const f32x4*)d_in[0];
    f32x4* out = (f32x4*)d_out;

    int total = in_sizes[0];              // 67108864 floats
    int num_rows = total / 4096;          // 16384
    int total_threads = num_rows * 128;   // 2097152

    dim3 block(256);
    dim3 grid((total_threads + 255) / 256);
    fwht_heads_shfl_nt<<<grid, block, 0, stream>>>(x, out, total_threads);
}